// Round 8
// baseline (236.114 us; speedup 1.0000x reference)
//
#include <hip/hip_runtime.h>

typedef unsigned short u16;
typedef __attribute__((ext_vector_type(8))) __bf16 bf16x8;
typedef __attribute__((ext_vector_type(8))) short short8;
typedef __attribute__((ext_vector_type(4))) short short4v;
typedef __attribute__((ext_vector_type(4))) float floatx4;

__device__ __forceinline__ u16 f2bf(float f){
  unsigned int x = __float_as_uint(f);
  unsigned int r = (x + 0x7fffu + ((x >> 16) & 1u)) >> 16;  // RTNE
  return (u16)r;
}

// async 16B global->LDS copy; lds base must be wave-uniform (HW: base + lane*16)
#define GLL(g, l) __builtin_amdgcn_global_load_lds( \
    (const __attribute__((address_space(1))) void*)(g), \
    (__attribute__((address_space(3))) void*)(l), 16, 0, 0)

// lane-rotate within each 16-lane row: lane i receives lane (i+1)&15's value.
// AMD DPP row_ror:N moves data toward HIGHER lanes (row_shr:1 == shfl_up(1)),
// so lane i <- lane (i+1) requires row_ror:15 = ctrl 0x12F (round-7 fix;
// 0x121 = row_ror:1 was the inverse rotation and failed absmax).
__device__ __forceinline__ bf16x8 ror1(bf16x8 v){
  union { bf16x8 h; int i[4]; } u, r;
  u.h = v;
#pragma unroll
  for (int k = 0; k < 4; ++k)
    r.i[k] = __builtin_amdgcn_mov_dpp(u.i[k], 0x12F, 0xf, 0xf, false);
  return r.h;
}

// ============================ PREP PASS =====================================
// blocks 0..1023: x[b][ci][t][y][zw] fp32 -> xp[b][t][y][zw][ci] bf16,
//   16B chunks XOR-placed: chunk position p holds ci-oct (p ^ (zw&7)).
//   LDS-staged transpose: float4 coalesced reads, coalesced b128 stores.
// blocks 1024..2319: weight fp32 -> wp[tap][kc][co][ci32] bf16 (coalesced reads).
__global__ void prep_kernel(const float* __restrict__ x, const float* __restrict__ w,
                            u16* __restrict__ xp, u16* __restrict__ wp){
  __shared__ __attribute__((aligned(16))) u16 I[16384];  // 32 KB: [ci][granule] swizzled
  const int bx = blockIdx.x;
  const int tid = threadIdx.x;
  if (bx < 1024){
    const int y = bx & 15, t = (bx >> 4) & 15, b = bx >> 8;
    const int l  = tid & 63;   // lane
    const int wv = tid >> 6;   // wave
    const float* xb = x + (size_t)b*64*65536 + t*4096 + y*256;

    // ---- Phase A: read + convert + swizzled LDS write ----
#pragma unroll
    for (int j = 0; j < 16; ++j){
      const int ci = j*4 + wv;
      const float4 f = *(const float4*)(xb + (size_t)ci*65536 + l*4);
      const int o  = ci >> 3;
      const int gp = l ^ o ^ ((o & 1) << 3);     // granule swizzle (bijective per ci)
      short4v hv;
      hv[0] = (short)f2bf(f.x);
      hv[1] = (short)f2bf(f.y);
      hv[2] = (short)f2bf(f.z);
      hv[3] = (short)f2bf(f.w);
      *(short4v*)(I + ci*256 + gp*4) = hv;       // b64, 8B aligned
    }
    __syncthreads();

    // ---- Phase B: gather + coalesced b128 global store ----
    const int p  = tid & 7;
    const int r0 = tid >> 3;
    u16* dst = xp + (size_t)bx*16384;
#pragma unroll
    for (int it = 0; it < 8; ++it){
      const int zw = it*32 + r0;
      const int o  = p ^ (zw & 7);
      const int g  = zw >> 2;
      const int gp = g ^ o ^ ((o & 1) << 3);
      const int base = gp*4 + (zw & 3);
      short8 vv;
#pragma unroll
      for (int m = 0; m < 8; ++m)
        vv[m] = (short)I[(o*8 + m)*256 + base];
      *(short8*)(dst + it*2048 + tid*8) = vv;    // 1 KB contiguous per wave-instr
    }
  } else {
    int idx = (bx - 1024)*256 + tid;   // linear over w input (coalesced)
    if (idx < 81*64*64){
      int r  = idx;
      int dw = r % 3; r /= 3;
      int dz = r % 3; r /= 3;
      int dy = r % 3; r /= 3;
      int ci = r & 63; r >>= 6;
      int co = r & 63; r >>= 6;
      int dt = r;
      int tap = ((dt*3 + dy)*3 + dz)*3 + dw;
      int kc = ci >> 5, ci32 = ci & 31;
      wp[tap*4096 + kc*2048 + co*32 + ci32] = f2bf(w[idx]);
    }
  }
}

// ============================ MAIN KERNEL ===================================
// v10 = v9 with the DPP rotate direction corrected (0x121 -> 0x12F).
// Structure: v8's dz-reuse (131 µs, MfmaUtil 60) + B-set read ONCE per dtdy
// (dw=0) and lane-rotated in-register for dw=1,2. The dw+1 B-fragment of
// lane (wl,q) is exactly lane ((wl+1)&15,q)'s dw fragment (row ww+1; chunk
// XOR follows each lane's own row; zz lane-uniform).
// ds_reads/dtdy: 108 -> 84; LDS pipe ~78 -> ~61 µs < MFMA 84 µs floor.
__global__ __launch_bounds__(256, 2) void conv4d_mfma_v10(
    const u16* __restrict__ xp, const u16* __restrict__ wp,
    const float* __restrict__ bias, float* __restrict__ out)
{
  __shared__ __attribute__((aligned(16))) u16 x_lds[16384];     // [zw][ci], XOR chunks
  __shared__ __attribute__((aligned(16))) u16 a_lds[2][12288];  // [dz][kc][co][ci32] x2

  // XCD-aware swizzle: XCD c = bx&7 owns (b = c>>1, y-half = c&1).
  const int bx = blockIdx.x;
  const int c = bx & 7, j = bx >> 3;
  const int b = c >> 1, t = j >> 3, y = (c & 1)*8 + (j & 7);

  const int tid  = threadIdx.x;
  const int lane = tid & 63;
  const int wv   = tid >> 6;
  const int wl   = lane & 15;   // B: n (w-pos); A: m (co row within 16-tile)
  const int q    = lane >> 4;   // k-octet selector; D: co = quad*4+reg

  floatx4 acc[4][4];
#pragma unroll
  for (int zi = 0; zi < 4; ++zi)
#pragma unroll
    for (int mi = 0; mi < 4; ++mi)
      acc[zi][mi] = (floatx4)0.0f;

  auto stage_x = [&](int dtdy){
    const int dt = dtdy / 3, dy = dtdy % 3;
    const int tt = (t + dt + 15) & 15;
    const int yy = (y + dy + 15) & 15;
    const u16* plane = xp + (size_t)(((b*16 + tt)*16) + yy) * 16384;
#pragma unroll
    for (int i = 0; i < 8; ++i)
      GLL(plane + wv*4096 + i*512 + lane*8, x_lds + wv*4096 + i*512);
  };
  // stage the dw-slab of (dtdy): taps {dtdy*9 + dz*3 + dw : dz=0,1,2},
  // three 8 KB regions at 12288-u16 stride -> a_lds[buf][dz*4096 ...]
  auto stage_a = [&](int dtdy, int dw, int buf){
    const u16* base = wp + (size_t)(dtdy*9 + dw) * 4096;
#pragma unroll
    for (int r = 0; r < 3; ++r)
#pragma unroll
      for (int i = 0; i < 2; ++i)
        GLL(base + (size_t)r*12288 + wv*1024 + i*512 + lane*8,
            a_lds[buf] + r*4096 + wv*1024 + i*512);
  };

  // prologue
  stage_x(0);
  stage_a(0, 0, 0);
  __syncthreads();   // drain: x plane 0 + first dw-slab ready

  bf16x8 bfr[2][6];   // persistent B set: [kc][jj], rotated across dw phases

  for (int dtdy = 0; dtdy < 9; ++dtdy){
#pragma unroll
    for (int dw = 0; dw < 3; ++dw){
      const int cur = (dtdy + dw) & 1;          // slab index (dtdy*3+dw) parity
      const bool boundary = (dw == 2);
      if (!boundary)
        stage_a(dtdy, dw + 1, cur ^ 1);          // async prefetch next dw-slab

      // ---- B set: ds_read at dw=0, DPP rotate for dw=1,2 ----
      if (dw == 0){
        const int ww = (wl + 15) & 15;
        const int wx = ww & 7;
#pragma unroll
        for (int kc = 0; kc < 2; ++kc){
          const int chunk = ((kc*4 + q) ^ wx)*8;
#pragma unroll
          for (int jj = 0; jj < 6; ++jj){
            const int zz = (wv*4 + jj + 15) & 15;
            bfr[kc][jj] = *(const bf16x8*)(x_lds + (zz*16 + ww)*64 + chunk);
          }
        }
      } else {
#pragma unroll
        for (int kc = 0; kc < 2; ++kc)
#pragma unroll
          for (int jj = 0; jj < 6; ++jj)
            bfr[kc][jj] = ror1(bfr[kc][jj]);
      }

      // ---- compute dw-slab: 2 kc x (12 af reads -> 48 MFMAs) ----
      const u16* abase = a_lds[cur] + wl*32 + q*8;
#pragma unroll
      for (int kc = 0; kc < 2; ++kc){
        bf16x8 af[3][4];
#pragma unroll
        for (int dz = 0; dz < 3; ++dz)
#pragma unroll
          for (int mi = 0; mi < 4; ++mi)
            af[dz][mi] = *(const bf16x8*)(abase + dz*4096 + kc*2048 + mi*512);
#pragma unroll
        for (int dz = 0; dz < 3; ++dz)
#pragma unroll
          for (int zi = 0; zi < 4; ++zi)
#pragma unroll
            for (int mi = 0; mi < 4; ++mi)
              acc[zi][mi] = __builtin_amdgcn_mfma_f32_16x16x32_bf16(
                  af[dz][mi], bfr[kc][zi + dz], acc[zi][mi], 0, 0, 0);
      }

      if (boundary){
        if (dtdy < 8){
          __syncthreads();                      // compute done: x_lds + a bufs free
          stage_x(dtdy + 1);
          stage_a(dtdy + 1, 0, cur ^ 1);
          __syncthreads();                      // drain x + a for next dtdy
        }
      } else {
        __syncthreads();                        // next dw-slab visible
      }
    }
  }

  // ---- epilogue: bias + fp32 store
  float bvals[4][4];
#pragma unroll
  for (int mi = 0; mi < 4; ++mi)
#pragma unroll
    for (int r = 0; r < 4; ++r)
      bvals[mi][r] = bias[mi*16 + q*4 + r];

  float* ob = out + (size_t)b*64*65536 + t*4096 + y*256 + wl;
#pragma unroll
  for (int zi = 0; zi < 4; ++zi){
    const int z = wv*4 + zi;
#pragma unroll
    for (int mi = 0; mi < 4; ++mi){
#pragma unroll
      for (int r = 0; r < 4; ++r){
        const int co = mi*16 + q*4 + r;   // C/D: row = quad*4 + reg
        ob[(size_t)co*65536 + z*16] = acc[zi][mi][r] + bvals[mi][r];
      }
    }
  }
}

// ===================== FALLBACK (round-2 proven path) =======================
__global__ void repack_w_kernel(const float* __restrict__ w, u16* __restrict__ wp){
  int idx = blockIdx.x * 256 + threadIdx.x;
  if (idx >= 81*64*64) return;
  int cw  = idx & 31;
  int t1  = idx >> 5;
  int co  = t1 & 63; t1 >>= 6;
  int kc  = t1 & 1;  t1 >>= 1;
  int tap = t1;
  int dw = tap % 3, dz = (tap/3) % 3, dy = (tap/9) % 3, dt = tap/27;
  int ci = kc*32 + cw;
  int in_idx = ((((dt*64 + co)*64 + ci)*3 + dy)*3 + dz)*3 + dw;
  wp[idx] = f2bf(w[in_idx]);
}

__global__ __launch_bounds__(256, 2) void conv4d_mfma_kernel(
    const float* __restrict__ x, const u16* __restrict__ wp,
    const float* __restrict__ bias, float* __restrict__ out)
{
  __shared__ __attribute__((aligned(16))) u16 x_lds[256*72];
  __shared__ __attribute__((aligned(16))) u16 a_lds[3*2*64*32];
  const int bx = blockIdx.x;
  const int y = bx & 15, t = (bx >> 4) & 15, b = bx >> 8;
  const int tid  = threadIdx.x;
  const int lane = tid & 63;
  const int wv   = tid >> 6;
  const int wl   = lane & 15;
  const int q    = lane >> 4;
  floatx4 acc[4][4];
#pragma unroll
  for (int zi = 0; zi < 4; ++zi)
#pragma unroll
    for (int mi = 0; mi < 4; ++mi)
      acc[zi][mi] = (floatx4)0.0f;
  const float* xb = x + (size_t)b * 64 * 65536;
  for (int dt = 0; dt < 3; ++dt){
    const int tt = (t + dt + 15) & 15;
    for (int dy = 0; dy < 3; ++dy){
      const int yy = (y + dy + 15) & 15;
      __syncthreads();
      {
        const float* src = xb + tt*4096 + yy*256 + tid;
#pragma unroll
        for (int oct = 0; oct < 8; ++oct){
          float v[8];
#pragma unroll
          for (int j = 0; j < 8; ++j)
            v[j] = src[(size_t)(oct*8 + j) * 65536];
          short8 vv;
#pragma unroll
          for (int j = 0; j < 8; ++j) vv[j] = (short)f2bf(v[j]);
          *(short8*)(x_lds + tid*72 + oct*8) = vv;
        }
      }
      for (int dz = 0; dz < 3; ++dz){
        const int tap0 = ((dt*3 + dy)*3 + dz)*3;
        __syncthreads();
        {
          const u16* asrc = wp + (size_t)tap0 * 4096;
#pragma unroll
          for (int i = 0; i < 6; ++i){
            int e = (i*256 + tid) * 8;
            *(short8*)(a_lds + e) = *(const short8*)(asrc + e);
          }
        }
        __syncthreads();
#pragma unroll
        for (int dw = 0; dw < 3; ++dw){
          const int ww = (wl + dw + 15) & 15;
#pragma unroll
          for (int kc = 0; kc < 2; ++kc){
            bf16x8 af[4];
#pragma unroll
            for (int mi = 0; mi < 4; ++mi)
              af[mi] = *(const bf16x8*)(a_lds + ((dw*2 + kc)*64 + mi*16 + wl)*32 + q*8);
#pragma unroll
            for (int zi = 0; zi < 4; ++zi){
              const int zz = (wv*4 + zi + dz + 15) & 15;
              bf16x8 bf = *(const bf16x8*)(x_lds + (zz*16 + ww)*72 + kc*32 + q*8);
#pragma unroll
              for (int mi = 0; mi < 4; ++mi)
                acc[zi][mi] = __builtin_amdgcn_mfma_f32_16x16x32_bf16(af[mi], bf, acc[zi][mi], 0, 0, 0);
            }
          }
        }
      }
    }
  }
  float bvals[4][4];
#pragma unroll
  for (int mi = 0; mi < 4; ++mi)
#pragma unroll
    for (int r = 0; r < 4; ++r)
      bvals[mi][r] = bias[mi*16 + q*4 + r];
  float* ob = out + (size_t)b * 64 * 65536 + t*4096 + y*256 + wl;
#pragma unroll
  for (int zi = 0; zi < 4; ++zi){
    const int z = wv*4 + zi;
#pragma unroll
    for (int mi = 0; mi < 4; ++mi){
#pragma unroll
      for (int r = 0; r < 4; ++r){
        const int co = mi*16 + q*4 + r;
        ob[(size_t)co*65536 + z*16] = acc[zi][mi][r] + bvals[mi][r];
      }
    }
  }
}

extern "C" void kernel_launch(void* const* d_in, const int* in_sizes, int n_in,
                              void* d_out, int out_size, void* d_ws, size_t ws_size,
                              hipStream_t stream) {
  const float* x    = (const float*)d_in[0];
  const float* w    = (const float*)d_in[1];
  const float* bias = (const float*)d_in[2];
  float* out = (float*)d_out;

  const size_t xp_bytes = (size_t)1024 * 16384 * 2;   // 33.55 MB bf16 transposed x
  const size_t wp_bytes = 81*64*64*2;                  // 663.5 KB packed weights
  if (ws_size >= xp_bytes + wp_bytes){
    u16* xp = (u16*)d_ws;
    u16* wp = (u16*)((char*)d_ws + xp_bytes);
    prep_kernel<<<1024 + 1296, 256, 0, stream>>>(x, w, xp, wp);
    conv4d_mfma_v10<<<1024, 256, 0, stream>>>(xp, wp, bias, out);
  } else {
    u16* wp = (u16*)d_ws;
    repack_w_kernel<<<1296, 256, 0, stream>>>(w, wp);
    conv4d_mfma_kernel<<<1024, 256, 0, stream>>>(x, wp, bias, out);
  }
}

// Round 9
// 231.919 us; speedup vs baseline: 1.0181x; 1.0181x over previous
//
#include <hip/hip_runtime.h>

typedef unsigned short u16;
typedef __attribute__((ext_vector_type(8))) __bf16 bf16x8;
typedef __attribute__((ext_vector_type(8))) short short8;
typedef __attribute__((ext_vector_type(4))) short short4v;
typedef __attribute__((ext_vector_type(4))) float floatx4;

__device__ __forceinline__ u16 f2bf(float f){
  unsigned int x = __float_as_uint(f);
  unsigned int r = (x + 0x7fffu + ((x >> 16) & 1u)) >> 16;  // RTNE
  return (u16)r;
}

// async 16B global->LDS copy; lds base must be wave-uniform (HW: base + lane*16)
#define GLL(g, l) __builtin_amdgcn_global_load_lds( \
    (const __attribute__((address_space(1))) void*)(g), \
    (__attribute__((address_space(3))) void*)(l), 16, 0, 0)

// lane-rotate within each 16-lane row: lane i receives lane (i+1)&15's value.
// AMD DPP row_ror:N moves data toward HIGHER lanes, so lane i <- lane (i+1)
// requires row_ror:15 = ctrl 0x12F (proven correct in round 8).
__device__ __forceinline__ bf16x8 ror1(bf16x8 v){
  union { bf16x8 h; int i[4]; } u, r;
  u.h = v;
#pragma unroll
  for (int k = 0; k < 4; ++k)
    r.i[k] = __builtin_amdgcn_mov_dpp(u.i[k], 0x12F, 0xf, 0xf, false);
  return r.h;
}

// ============================ PREP PASS =====================================
// blocks 0..1023: x[b][ci][t][y][zw] fp32 -> xp[b][t][y][zw][ci] bf16,
//   16B chunks XOR-placed: chunk position p holds ci-oct (p ^ (zw&7)).
//   LDS-staged transpose: float4 coalesced reads, coalesced b128 stores.
// blocks 1024..2319: weight fp32 -> wp[tap][kc][co][ci32] bf16 (coalesced reads).
__global__ void prep_kernel(const float* __restrict__ x, const float* __restrict__ w,
                            u16* __restrict__ xp, u16* __restrict__ wp){
  __shared__ __attribute__((aligned(16))) u16 I[16384];  // 32 KB: [ci][granule] swizzled
  const int bx = blockIdx.x;
  const int tid = threadIdx.x;
  if (bx < 1024){
    const int y = bx & 15, t = (bx >> 4) & 15, b = bx >> 8;
    const int l  = tid & 63;   // lane
    const int wv = tid >> 6;   // wave
    const float* xb = x + (size_t)b*64*65536 + t*4096 + y*256;

    // ---- Phase A: read + convert + swizzled LDS write ----
#pragma unroll
    for (int j = 0; j < 16; ++j){
      const int ci = j*4 + wv;
      const float4 f = *(const float4*)(xb + (size_t)ci*65536 + l*4);
      const int o  = ci >> 3;
      const int gp = l ^ o ^ ((o & 1) << 3);     // granule swizzle (bijective per ci)
      short4v hv;
      hv[0] = (short)f2bf(f.x);
      hv[1] = (short)f2bf(f.y);
      hv[2] = (short)f2bf(f.z);
      hv[3] = (short)f2bf(f.w);
      *(short4v*)(I + ci*256 + gp*4) = hv;       // b64, 8B aligned
    }
    __syncthreads();

    // ---- Phase B: gather + coalesced b128 global store ----
    const int p  = tid & 7;
    const int r0 = tid >> 3;
    u16* dst = xp + (size_t)bx*16384;
#pragma unroll
    for (int it = 0; it < 8; ++it){
      const int zw = it*32 + r0;
      const int o  = p ^ (zw & 7);
      const int g  = zw >> 2;
      const int gp = g ^ o ^ ((o & 1) << 3);
      const int base = gp*4 + (zw & 3);
      short8 vv;
#pragma unroll
      for (int m = 0; m < 8; ++m)
        vv[m] = (short)I[(o*8 + m)*256 + base];
      *(short8*)(dst + it*2048 + tid*8) = vv;    // 1 KB contiguous per wave-instr
    }
  } else {
    int idx = (bx - 1024)*256 + tid;   // linear over w input (coalesced)
    if (idx < 81*64*64){
      int r  = idx;
      int dw = r % 3; r /= 3;
      int dz = r % 3; r /= 3;
      int dy = r % 3; r /= 3;
      int ci = r & 63; r >>= 6;
      int co = r & 63; r >>= 6;
      int dt = r;
      int tap = ((dt*3 + dy)*3 + dz)*3 + dw;
      int kc = ci >> 5, ci32 = ci & 31;
      wp[tap*4096 + kc*2048 + co*32 + ci32] = f2bf(w[idx]);
    }
  }
}

// ============================ MAIN KERNEL ===================================
// v11 = v10 minus x_lds. Evidence: x_lds is a VERBATIM linear copy of the xp
// plane, so the dw=0 B-gather reads global xp directly (per-lane 16 B, L2-hot);
// DPP rotate (proven) covers dw=1,2. Deletes stage_x (8 GLL/dtdy), the
// x-boundary barriers, and 12 LDS reads/dtdy:
//   LDS reads/dtdy/wave 84 -> 72 (af only), LDS 80 -> 48 KB (3 blocks/CU),
//   barriers 36 -> 27 (uniform phases; a-prefetch crosses dtdy boundaries).
// SQ_LDS_BANK_CONFLICT is invariant 1.062e7 across v4/v8/v10 => it tracks GLL
// staging writes; halving staged bytes tests that hypothesis directly.
__global__ __launch_bounds__(256, 2) void conv4d_mfma_v11(
    const u16* __restrict__ xp, const u16* __restrict__ wp,
    const float* __restrict__ bias, float* __restrict__ out)
{
  __shared__ __attribute__((aligned(16))) u16 a_lds[2][12288];  // [dz][kc][co][ci32] x2

  // XCD-aware swizzle: XCD c = bx&7 owns (b = c>>1, y-half = c&1).
  const int bx = blockIdx.x;
  const int c = bx & 7, j = bx >> 3;
  const int b = c >> 1, t = j >> 3, y = (c & 1)*8 + (j & 7);

  const int tid  = threadIdx.x;
  const int lane = tid & 63;
  const int wv   = tid >> 6;
  const int wl   = lane & 15;   // B: n (w-pos); A: m (co row within 16-tile)
  const int q    = lane >> 4;   // k-octet selector; D: co = quad*4+reg

  floatx4 acc[4][4];
#pragma unroll
  for (int zi = 0; zi < 4; ++zi)
#pragma unroll
    for (int mi = 0; mi < 4; ++mi)
      acc[zi][mi] = (floatx4)0.0f;

  // stage the dw-slab of (dtdy): taps {dtdy*9 + dz*3 + dw : dz=0,1,2},
  // three 8 KB regions at 12288-u16 stride -> a_lds[buf][dz*4096 ...]
  auto stage_a = [&](int dtdy, int dw, int buf){
    const u16* base = wp + (size_t)(dtdy*9 + dw) * 4096;
#pragma unroll
    for (int r = 0; r < 3; ++r)
#pragma unroll
      for (int i = 0; i < 2; ++i)
        GLL(base + (size_t)r*12288 + wv*1024 + i*512 + lane*8,
            a_lds[buf] + r*4096 + wv*1024 + i*512);
  };

  // prologue
  stage_a(0, 0, 0);
  __syncthreads();   // first dw-slab ready

  bf16x8 bfr[2][6];   // persistent B set: [kc][jj], rotated across dw phases

  for (int dtdy = 0; dtdy < 9; ++dtdy){
    const int dt = dtdy / 3, dy = dtdy % 3;
    const int tt = (t + dt + 15) & 15;
    const int yy = (y + dy + 15) & 15;
    const u16* plane = xp + (size_t)(((b*16 + tt)*16) + yy) * 16384;

    // ---- dw=0 B set: direct global gather (x_lds was a linear plane copy,
    //      so the addresses are identical; no LDS, no barrier dependency ->
    //      compiler may hoist these above the previous barrier) ----
    {
      const int ww = (wl + 15) & 15;
      const int wx = ww & 7;
#pragma unroll
      for (int kc = 0; kc < 2; ++kc){
        const int chunk = ((kc*4 + q) ^ wx)*8;
#pragma unroll
        for (int jj = 0; jj < 6; ++jj){
          const int zz = (wv*4 + jj + 15) & 15;
          bfr[kc][jj] = *(const bf16x8*)(plane + (zz*16 + ww)*64 + chunk);
        }
      }
    }

#pragma unroll
    for (int dw = 0; dw < 3; ++dw){
      const int cur = (dtdy + dw) & 1;          // phase p = dtdy*3+dw; cur = p&1
      // async prefetch next dw-slab (crosses the dtdy boundary now)
      if (dw < 2)                stage_a(dtdy, dw + 1, cur ^ 1);
      else if (dtdy < 8)         stage_a(dtdy + 1, 0, cur ^ 1);

      // ---- B set: rotate for dw=1,2 ----
      if (dw){
#pragma unroll
        for (int kc = 0; kc < 2; ++kc)
#pragma unroll
          for (int jj = 0; jj < 6; ++jj)
            bfr[kc][jj] = ror1(bfr[kc][jj]);
      }

      // ---- compute dw-slab: 2 kc x (12 af reads -> 48 MFMAs) ----
      const u16* abase = a_lds[cur] + wl*32 + q*8;
#pragma unroll
      for (int kc = 0; kc < 2; ++kc){
        bf16x8 af[3][4];
#pragma unroll
        for (int dz = 0; dz < 3; ++dz)
#pragma unroll
          for (int mi = 0; mi < 4; ++mi)
            af[dz][mi] = *(const bf16x8*)(abase + dz*4096 + kc*2048 + mi*512);
#pragma unroll
        for (int dz = 0; dz < 3; ++dz)
#pragma unroll
          for (int zi = 0; zi < 4; ++zi)
#pragma unroll
            for (int mi = 0; mi < 4; ++mi)
              acc[zi][mi] = __builtin_amdgcn_mfma_f32_16x16x32_bf16(
                  af[dz][mi], bfr[kc][zi + dz], acc[zi][mi], 0, 0, 0);
      }

      if (!(dtdy == 8 && dw == 2))
        __syncthreads();                        // next slab visible / cur free
    }
  }

  // ---- epilogue: bias + fp32 store
  float bvals[4][4];
#pragma unroll
  for (int mi = 0; mi < 4; ++mi)
#pragma unroll
    for (int r = 0; r < 4; ++r)
      bvals[mi][r] = bias[mi*16 + q*4 + r];

  float* ob = out + (size_t)b*64*65536 + t*4096 + y*256 + wl;
#pragma unroll
  for (int zi = 0; zi < 4; ++zi){
    const int z = wv*4 + zi;
#pragma unroll
    for (int mi = 0; mi < 4; ++mi){
#pragma unroll
      for (int r = 0; r < 4; ++r){
        const int co = mi*16 + q*4 + r;   // C/D: row = quad*4 + reg
        ob[(size_t)co*65536 + z*16] = acc[zi][mi][r] + bvals[mi][r];
      }
    }
  }
}

// ===================== FALLBACK (round-2 proven path) =======================
__global__ void repack_w_kernel(const float* __restrict__ w, u16* __restrict__ wp){
  int idx = blockIdx.x * 256 + threadIdx.x;
  if (idx >= 81*64*64) return;
  int cw  = idx & 31;
  int t1  = idx >> 5;
  int co  = t1 & 63; t1 >>= 6;
  int kc  = t1 & 1;  t1 >>= 1;
  int tap = t1;
  int dw = tap % 3, dz = (tap/3) % 3, dy = (tap/9) % 3, dt = tap/27;
  int ci = kc*32 + cw;
  int in_idx = ((((dt*64 + co)*64 + ci)*3 + dy)*3 + dz)*3 + dw;
  wp[idx] = f2bf(w[in_idx]);
}

__global__ __launch_bounds__(256, 2) void conv4d_mfma_kernel(
    const float* __restrict__ x, const u16* __restrict__ wp,
    const float* __restrict__ bias, float* __restrict__ out)
{
  __shared__ __attribute__((aligned(16))) u16 x_lds[256*72];
  __shared__ __attribute__((aligned(16))) u16 a_lds[3*2*64*32];
  const int bx = blockIdx.x;
  const int y = bx & 15, t = (bx >> 4) & 15, b = bx >> 8;
  const int tid  = threadIdx.x;
  const int lane = tid & 63;
  const int wv   = tid >> 6;
  const int wl   = lane & 15;
  const int q    = lane >> 4;
  floatx4 acc[4][4];
#pragma unroll
  for (int zi = 0; zi < 4; ++zi)
#pragma unroll
    for (int mi = 0; mi < 4; ++mi)
      acc[zi][mi] = (floatx4)0.0f;
  const float* xb = x + (size_t)b * 64 * 65536;
  for (int dt = 0; dt < 3; ++dt){
    const int tt = (t + dt + 15) & 15;
    for (int dy = 0; dy < 3; ++dy){
      const int yy = (y + dy + 15) & 15;
      __syncthreads();
      {
        const float* src = xb + tt*4096 + yy*256 + tid;
#pragma unroll
        for (int oct = 0; oct < 8; ++oct){
          float v[8];
#pragma unroll
          for (int j = 0; j < 8; ++j)
            v[j] = src[(size_t)(oct*8 + j) * 65536];
          short8 vv;
#pragma unroll
          for (int j = 0; j < 8; ++j) vv[j] = (short)f2bf(v[j]);
          *(short8*)(x_lds + tid*72 + oct*8) = vv;
        }
      }
      for (int dz = 0; dz < 3; ++dz){
        const int tap0 = ((dt*3 + dy)*3 + dz)*3;
        __syncthreads();
        {
          const u16* asrc = wp + (size_t)tap0 * 4096;
#pragma unroll
          for (int i = 0; i < 6; ++i){
            int e = (i*256 + tid) * 8;
            *(short8*)(a_lds + e) = *(const short8*)(asrc + e);
          }
        }
        __syncthreads();
#pragma unroll
        for (int dw = 0; dw < 3; ++dw){
          const int ww = (wl + dw + 15) & 15;
#pragma unroll
          for (int kc = 0; kc < 2; ++kc){
            bf16x8 af[4];
#pragma unroll
            for (int mi = 0; mi < 4; ++mi)
              af[mi] = *(const bf16x8*)(a_lds + ((dw*2 + kc)*64 + mi*16 + wl)*32 + q*8);
#pragma unroll
            for (int zi = 0; zi < 4; ++zi){
              const int zz = (wv*4 + zi + dz + 15) & 15;
              bf16x8 bf = *(const bf16x8*)(x_lds + (zz*16 + ww)*72 + kc*32 + q*8);
#pragma unroll
              for (int mi = 0; mi < 4; ++mi)
                acc[zi][mi] = __builtin_amdgcn_mfma_f32_16x16x32_bf16(af[mi], bf, acc[zi][mi], 0, 0, 0);
            }
          }
        }
      }
    }
  }
  float bvals[4][4];
#pragma unroll
  for (int mi = 0; mi < 4; ++mi)
#pragma unroll
    for (int r = 0; r < 4; ++r)
      bvals[mi][r] = bias[mi*16 + q*4 + r];
  float* ob = out + (size_t)b * 64 * 65536 + t*4096 + y*256 + wl;
#pragma unroll
  for (int zi = 0; zi < 4; ++zi){
    const int z = wv*4 + zi;
#pragma unroll
    for (int mi = 0; mi < 4; ++mi){
#pragma unroll
      for (int r = 0; r < 4; ++r){
        const int co = mi*16 + q*4 + r;
        ob[(size_t)co*65536 + z*16] = acc[zi][mi][r] + bvals[mi][r];
      }
    }
  }
}

extern "C" void kernel_launch(void* const* d_in, const int* in_sizes, int n_in,
                              void* d_out, int out_size, void* d_ws, size_t ws_size,
                              hipStream_t stream) {
  const float* x    = (const float*)d_in[0];
  const float* w    = (const float*)d_in[1];
  const float* bias = (const float*)d_in[2];
  float* out = (float*)d_out;

  const size_t xp_bytes = (size_t)1024 * 16384 * 2;   // 33.55 MB bf16 transposed x
  const size_t wp_bytes = 81*64*64*2;                  // 663.5 KB packed weights
  if (ws_size >= xp_bytes + wp_bytes){
    u16* xp = (u16*)d_ws;
    u16* wp = (u16*)((char*)d_ws + xp_bytes);
    prep_kernel<<<1024 + 1296, 256, 0, stream>>>(x, w, xp, wp);
    conv4d_mfma_v11<<<1024, 256, 0, stream>>>(xp, wp, bias, out);
  } else {
    u16* wp = (u16*)d_ws;
    repack_w_kernel<<<1296, 256, 0, stream>>>(w, wp);
    conv4d_mfma_kernel<<<1024, 256, 0, stream>>>(x, wp, bias, out);
  }
}